// Round 15
// baseline (32.591 us; speedup 1.0000x reference)
//
#include <hip/hip_runtime.h>

#define F_ALPHA 0.25f
#define F_EPS   1e-8f
#define NB 4   // preds per block

// R14 body + REGISTER PINNING of all block-uniform pred state.
// R12 diag: VGPR_Count=32 with ~44 live values needed -> allocator was
// re-loading pred boxes + recomputing conversions/addresses per body
// (~200 extra VALU/body). Opaque asm makes rematerialization illegal.
__global__ void __launch_bounds__(256, 4)
fused_cost_kernel(const float* __restrict__ logits,      // [N, C]
                  const float4* __restrict__ pred_boxes, // [N]
                  const float4* __restrict__ tgt_boxes,  // [T]
                  const int* __restrict__ tgt_ids,       // [T]
                  float* __restrict__ out,               // [N, T]
                  int N, int C, int T) {
    __shared__ float4 fclsT[96];                         // [class] -> NB costs
    const int n0  = blockIdx.x * NB;
    const int tid = threadIdx.x;

    // ---- phase 1: wave w computes pred (n0+w)'s focal row, transposed ----
    {
        const int w = tid >> 6, l = tid & 63;
        const float* lrow = logits + (size_t)(n0 + w) * C;
        for (int c = l; c < C; c += 64) {
            float x = lrow[c];
            float p = 1.0f / (1.0f + expf(-x));
            float om = 1.0f - p;
            float pos = F_ALPHA * om * om * (-logf(p + F_EPS));
            float neg = (1.0f - F_ALPHA) * p * p * (-logf(om + F_EPS));
            ((float*)fclsT)[c * NB + w] = 2.0f * (pos - neg) + 2.0f; // 2*cls+2
        }
    }

    // pred-side params (block-uniform) — computed ONCE, pinned into VGPRs
    float pcx[NB], pcy[NB], pw_[NB], ph_[NB];
    float px1[NB], py1[NB], px2[NB], py2[NB], parea[NB];
    float* op[NB];
#pragma unroll
    for (int i = 0; i < NB; ++i) {
        const int n = n0 + i;                            // N % NB == 0
        float4 pb = pred_boxes[n];
        pcx[i] = pb.x; pcy[i] = pb.y; pw_[i] = pb.z; ph_[i] = pb.w;
        px1[i] = fmaf(-0.5f, pb.z, pb.x);  py1[i] = fmaf(-0.5f, pb.w, pb.y);
        px2[i] = fmaf( 0.5f, pb.z, pb.x);  py2[i] = fmaf( 0.5f, pb.w, pb.y);
        parea[i] = pb.z * pb.w;
        op[i] = out + (size_t)n * T;
        // pin: opaque to the optimizer -> cannot re-load/recompute in the loop
        asm volatile("" : "+v"(pcx[i]), "+v"(pcy[i]), "+v"(pw_[i]), "+v"(ph_[i]));
        asm volatile("" : "+v"(px1[i]), "+v"(py1[i]), "+v"(px2[i]), "+v"(py2[i]));
        asm volatile("" : "+v"(parea[i]), "+v"(op[i]));
    }
    __syncthreads();

    auto body = [&](int t) {
        float4 tb = tgt_boxes[t];                        // unit-stride float4
        int id = tgt_ids[t];                             // unit-stride dword
        float4 cls4 = fclsT[id];                         // one ds_read_b128
        const float clsv[NB] = {cls4.x, cls4.y, cls4.z, cls4.w};

        float tx1 = fmaf(-0.5f, tb.z, tb.x), ty1 = fmaf(-0.5f, tb.w, tb.y);
        float tx2 = fmaf( 0.5f, tb.z, tb.x), ty2 = fmaf( 0.5f, tb.w, tb.y);
        float tarea = tb.z * tb.w;

#pragma unroll
        for (int i = 0; i < NB; ++i) {
            float ax = fmaxf(px1[i], tx1), bx = fminf(px2[i], tx2);
            float ay = fmaxf(py1[i], ty1), by = fminf(py2[i], ty2);
            float dx = bx - ax, dy = by - ay;
            float iw = fmaxf(dx, 0.0f), ih = fmaxf(dy, 0.0f);
            float inter = iw * ih;
            float uni = (parea[i] + tarea) - inter;

            float ew = (pw_[i] + tb.z) - dx;             // enclosing identity
            float eh = (ph_[i] + tb.w) - dy;
            float earea = ew * eh;

            float l1 = (fabsf(pcx[i] - tb.x) + fabsf(pcy[i] - tb.y))
                     + (fabsf(pw_[i] - tb.z) + fabsf(ph_[i] - tb.w));

            // 2*inter/uni + 2*uni/earea = 2*(inter*earea + uni^2)*rcp(uni*earea)
            float den = uni * earea;
            float r   = __builtin_amdgcn_rcpf(den);
            float num = fmaf(uni, uni, inter * earea);

            float v = fmaf(5.0f, l1, clsv[i]);           // 5*l1 + 2*cls + 2
            v = fmaf(-2.0f, num * r, v);
            op[i][t] = v;                                // coalesced dword store
        }
    };

    // ---- phase 2: unrolled-by-2 target sweep ----
    int t = tid;
    for (; t + 256 < T; t += 512) { body(t); body(t + 256); }
    for (; t < T; t += 256) body(t);
}

extern "C" void kernel_launch(void* const* d_in, const int* in_sizes, int n_in,
                              void* d_out, int out_size, void* d_ws, size_t ws_size,
                              hipStream_t stream) {
    const float* logits = (const float*)d_in[0];   // [bs, Q, C]
    const float* pboxes = (const float*)d_in[1];   // [bs, Q, 4]
    const float* tboxes = (const float*)d_in[2];   // [T, 4]
    const int*   tids   = (const int*)d_in[3];     // [T]

    int N = in_sizes[1] / 4;          // bs*Q = 14400
    int C = in_sizes[0] / N;          // 91
    int T = in_sizes[2] / 4;          // 1600

    int grid = N / NB;                // 3600
    fused_cost_kernel<<<grid, 256, 0, stream>>>(
        logits, (const float4*)pboxes, (const float4*)tboxes, tids,
        (float*)d_out, N, C, T);
}

// Round 16
// 31.409 us; speedup vs baseline: 1.0376x; 1.0376x over previous
//
#include <hip/hip_runtime.h>

#define F_ALPHA 0.25f
#define F_EPS   1e-8f
#define NB 4   // preds per block

// R14 base (best: 31.6us) + unroll-4 target sweep (ILP probe: latency-bound
// hypothesis — 4 independent bodies = 16 pair-chains in flight, all global
// loads for the pass issued before any compute).
__global__ void __launch_bounds__(256, 4)
fused_cost_kernel(const float* __restrict__ logits,      // [N, C]
                  const float4* __restrict__ pred_boxes, // [N]
                  const float4* __restrict__ tgt_boxes,  // [T]
                  const int* __restrict__ tgt_ids,       // [T]
                  float* __restrict__ out,               // [N, T]
                  int N, int C, int T) {
    __shared__ float4 fclsT[96];                         // [class] -> NB costs
    const int n0  = blockIdx.x * NB;
    const int tid = threadIdx.x;

    // ---- phase 1: wave w computes pred (n0+w)'s focal row, transposed ----
    {
        const int w = tid >> 6, l = tid & 63;
        const float* lrow = logits + (size_t)(n0 + w) * C;
        for (int c = l; c < C; c += 64) {
            float x = lrow[c];
            float p = 1.0f / (1.0f + expf(-x));
            float om = 1.0f - p;
            float pos = F_ALPHA * om * om * (-logf(p + F_EPS));
            float neg = (1.0f - F_ALPHA) * p * p * (-logf(om + F_EPS));
            ((float*)fclsT)[c * NB + w] = 2.0f * (pos - neg) + 2.0f; // 2*cls+2
        }
    }

    // pred-side params (block-uniform)
    float pcx[NB], pcy[NB], pw_[NB], ph_[NB];
    float px1[NB], py1[NB], px2[NB], py2[NB], parea[NB];
    float* op[NB];
#pragma unroll
    for (int i = 0; i < NB; ++i) {
        const int n = n0 + i;                            // N % NB == 0
        float4 pb = pred_boxes[n];
        pcx[i] = pb.x; pcy[i] = pb.y; pw_[i] = pb.z; ph_[i] = pb.w;
        px1[i] = fmaf(-0.5f, pb.z, pb.x);  py1[i] = fmaf(-0.5f, pb.w, pb.y);
        px2[i] = fmaf( 0.5f, pb.z, pb.x);  py2[i] = fmaf( 0.5f, pb.w, pb.y);
        parea[i] = pb.z * pb.w;
        op[i] = out + (size_t)n * T;
    }
    __syncthreads();

    auto body = [&](int t) {
        float4 tb = tgt_boxes[t];                        // unit-stride float4
        int id = tgt_ids[t];                             // unit-stride dword
        float4 cls4 = fclsT[id];                         // one ds_read_b128
        const float clsv[NB] = {cls4.x, cls4.y, cls4.z, cls4.w};

        float tx1 = fmaf(-0.5f, tb.z, tb.x), ty1 = fmaf(-0.5f, tb.w, tb.y);
        float tx2 = fmaf( 0.5f, tb.z, tb.x), ty2 = fmaf( 0.5f, tb.w, tb.y);
        float tarea = tb.z * tb.w;

#pragma unroll
        for (int i = 0; i < NB; ++i) {
            float ax = fmaxf(px1[i], tx1), bx = fminf(px2[i], tx2);
            float ay = fmaxf(py1[i], ty1), by = fminf(py2[i], ty2);
            float dx = bx - ax, dy = by - ay;
            float iw = fmaxf(dx, 0.0f), ih = fmaxf(dy, 0.0f);
            float inter = iw * ih;
            float uni = (parea[i] + tarea) - inter;

            float ew = (pw_[i] + tb.z) - dx;             // enclosing identity
            float eh = (ph_[i] + tb.w) - dy;
            float earea = ew * eh;

            float l1 = (fabsf(pcx[i] - tb.x) + fabsf(pcy[i] - tb.y))
                     + (fabsf(pw_[i] - tb.z) + fabsf(ph_[i] - tb.w));

            // 2*inter/uni + 2*uni/earea = 2*(inter*earea + uni^2)*rcp(uni*earea)
            float den = uni * earea;
            float r   = __builtin_amdgcn_rcpf(den);
            float num = fmaf(uni, uni, inter * earea);

            float v = fmaf(5.0f, l1, clsv[i]);           // 5*l1 + 2*cls + 2
            v = fmaf(-2.0f, num * r, v);
            op[i][t] = v;                                // coalesced dword store
        }
    };

    // ---- phase 2: unroll-4 target sweep (ILP x2 vs R14) ----
    int t = tid;
    for (; t + 768 < T; t += 1024) {
        body(t); body(t + 256); body(t + 512); body(t + 768);
    }
    for (; t < T; t += 256) body(t);
}

extern "C" void kernel_launch(void* const* d_in, const int* in_sizes, int n_in,
                              void* d_out, int out_size, void* d_ws, size_t ws_size,
                              hipStream_t stream) {
    const float* logits = (const float*)d_in[0];   // [bs, Q, C]
    const float* pboxes = (const float*)d_in[1];   // [bs, Q, 4]
    const float* tboxes = (const float*)d_in[2];   // [T, 4]
    const int*   tids   = (const int*)d_in[3];     // [T]

    int N = in_sizes[1] / 4;          // bs*Q = 14400
    int C = in_sizes[0] / N;          // 91
    int T = in_sizes[2] / 4;          // 1600

    int grid = N / NB;                // 3600
    fused_cost_kernel<<<grid, 256, 0, stream>>>(
        logits, (const float4*)pboxes, (const float4*)tboxes, tids,
        (float*)d_out, N, C, T);
}